// Round 8
// baseline (26.435 us; speedup 1.0000x reference)
//
#include <hip/hip_runtime.h>
#include <float.h>
#include <math.h>

// Problem constants (from reference)
constexpr int B  = 16;
constexpr int VS = 10475;
constexpr int VO = 8192;
constexpr int K  = 64;
constexpr int PS = 1024;
constexpr int PO = 2048;

// Geometry (R6 base): 256 blocks (1/CU) x 256 threads (4 waves).
// Block = (k, 256-query chunk); all 2048 objects of k staged in LDS.
// R8 change: QUARTER-wave jgroups (16 lanes), QL=16 queries/lane ->
// ds_read count per block halves (PO/4 = 512). Object ownership is
// INTERLEAVED (group g reads so[16*jj+g]) so each wave's 4 broadcast
// addresses are 64 contiguous bytes = 16 distinct banks (conflict-free).
constexpr int BLK  = 256;
constexpr int QPB  = 256;              // queries per block
constexpr int GRID = K * (PS / QPB);   // 256
constexpr int NG   = 16;               // jgroups (quarter-waves) per block
constexpr int JPG  = PO / NG;          // 128 objects per jgroup
constexpr int QL   = 16;               // queries per lane (8 packed pairs)

typedef float v2f __attribute__((ext_vector_type(2)));
typedef float v4f __attribute__((ext_vector_type(4)));

// ---------------- kernel 1: full min + block partial sum ----------------

__global__ __launch_bounds__(BLK)
void cl_onepass(const float* __restrict__ smplx_v,
                const float* __restrict__ object_v,
                const int*   __restrict__ spi,
                const int*   __restrict__ opi,
                const int*   __restrict__ bidx,
                float*       __restrict__ partial)   // [GRID]
{
    __shared__ v4f    so[PO];        // (x,y,z, 0.5*|o|^2) -> 32 KiB
    __shared__ float4 qld[QPB];      // (x,y,z, |s|^2)     ->  4 KiB
    __shared__ float  red[NG][QPB];  //                    -> 16 KiB
    __shared__ float  rsum[BLK];

    const int bk  = blockIdx.x;
    const int tid = threadIdx.x;
    const int k   = bk >> 2;
    const int ic  = bk & 3;
    const int b   = bidx[k];

    // ---- gather: all 2048 objects of this k into LDS ----
    const float* __restrict__ ov = object_v + (size_t)b * VO * 3;
    #pragma unroll
    for (int r = 0; r < PO / BLK; ++r) {
        const int j  = r * BLK + tid;
        const int oj = opi[k * PO + j];
        const float x = ov[oj * 3 + 0];
        const float y = ov[oj * 3 + 1];
        const float z = ov[oj * 3 + 2];
        so[j] = (v4f){x, y, z, 0.5f * (x * x + y * y + z * z)};
    }
    // ---- gather: this block's 256 queries ----
    {
        const int i  = ic * QPB + tid;
        const int si = spi[k * PS + i];
        const float* __restrict__ sv = smplx_v + ((size_t)b * VS + si) * 3;
        const float x = sv[0], y = sv[1], z = sv[2];
        qld[tid] = make_float4(x, y, z, x * x + y * y + z * z);
    }
    __syncthreads();

    // ---- setup: lane owns 16 queries as 8 packed pairs ----
    const int g  = tid >> 4;         // jgroup 0..15 (quarter-wave)
    const int gl = tid & 15;
    const int qb = gl * QL;

    v2f nsx[8], nsy[8], nsz[8], mint[8];
    #pragma unroll
    for (int p = 0; p < 8; ++p) {
        const float4 qa = qld[qb + 2 * p];
        const float4 qc = qld[qb + 2 * p + 1];
        nsx[p] = (v2f){-qa.x, -qc.x};
        nsy[p] = (v2f){-qa.y, -qc.y};
        nsz[p] = (v2f){-qa.z, -qc.z};
        mint[p] = (v2f){FLT_MAX, FLT_MAX};
    }

    // ---- hot loop: min over this jgroup's 128 objects, 2 per iter ----
    // Interleaved ownership: group g owns objects {16*jj + g}.
    // t = 0.5*|o|^2 - s.o for 2 queries per v_pk_fma_f32 (op_sel splats the
    // object components from the (x,y),(z,w) register pairs — proven R6).
    // Nested fminf -> v_min3_f32.
    #pragma unroll 2
    for (int m = 0; m < JPG / 2; ++m) {
        const v4f o0 = so[(2 * m) * NG + g];
        const v4f o1 = so[(2 * m + 1) * NG + g];
        const v2f o0xy = __builtin_shufflevector(o0, o0, 0, 1);
        const v2f o0zw = __builtin_shufflevector(o0, o0, 2, 3);
        const v2f o1xy = __builtin_shufflevector(o1, o1, 0, 1);
        const v2f o1zw = __builtin_shufflevector(o1, o1, 2, 3);
        #pragma unroll
        for (int p = 0; p < 8; ++p) {
            v2f t0, t1;
            asm("v_pk_fma_f32 %0, %1, %2, %3 op_sel:[0,0,1] op_sel_hi:[0,1,1]"
                : "=v"(t0) : "v"(o0xy), "v"(nsx[p]), "v"(o0zw));
            asm("v_pk_fma_f32 %0, %1, %2, %0 op_sel:[1,0,0] op_sel_hi:[1,1,1]"
                : "+v"(t0) : "v"(o0xy), "v"(nsy[p]));
            asm("v_pk_fma_f32 %0, %1, %2, %0 op_sel:[0,0,0] op_sel_hi:[0,1,1]"
                : "+v"(t0) : "v"(o0zw), "v"(nsz[p]));
            asm("v_pk_fma_f32 %0, %1, %2, %3 op_sel:[0,0,1] op_sel_hi:[0,1,1]"
                : "=v"(t1) : "v"(o1xy), "v"(nsx[p]), "v"(o1zw));
            asm("v_pk_fma_f32 %0, %1, %2, %0 op_sel:[1,0,0] op_sel_hi:[1,1,1]"
                : "+v"(t1) : "v"(o1xy), "v"(nsy[p]));
            asm("v_pk_fma_f32 %0, %1, %2, %0 op_sel:[0,0,0] op_sel_hi:[0,1,1]"
                : "+v"(t1) : "v"(o1zw), "v"(nsz[p]));
            mint[p].x = fminf(mint[p].x, fminf(t0.x, t1.x));   // v_min3_f32
            mint[p].y = fminf(mint[p].y, fminf(t0.y, t1.y));
        }
    }

    // ---- cross-jgroup min via LDS ----
    #pragma unroll
    for (int p = 0; p < 8; ++p) {
        red[g][qb + 2 * p]     = mint[p].x;
        red[g][qb + 2 * p + 1] = mint[p].y;
    }
    __syncthreads();

    // thread t finalizes query t of this block
    float mq = red[0][tid];
    #pragma unroll
    for (int g2 = 1; g2 < NG; ++g2) mq = fminf(mq, red[g2][tid]);
    const float s2q = qld[tid].w;
    const float d   = sqrtf(fmaxf(fmaf(2.0f, mq, s2q), 0.0f));

    // ---- deterministic block tree-sum ----
    rsum[tid] = d;
    __syncthreads();
    for (int s = BLK / 2; s > 0; s >>= 1) {
        if (tid < s) rsum[tid] += rsum[tid + s];
        __syncthreads();
    }
    if (tid == 0) partial[bk] = rsum[0];
}

// ---------------- kernel 2: final 256 -> 1 reduce ----------------

__global__ __launch_bounds__(GRID)
void cl_final(const float* __restrict__ partial, float* __restrict__ out)
{
    __shared__ float red[GRID];
    const int tid = threadIdx.x;
    red[tid] = partial[tid];
    __syncthreads();
    for (int s = GRID / 2; s > 0; s >>= 1) {
        if (tid < s) red[tid] += red[tid + s];
        __syncthreads();
    }
    if (tid == 0) out[0] = red[0] * (1.0f / (float)(K * PS));
}

// ---------------- launcher ----------------

extern "C" void kernel_launch(void* const* d_in, const int* in_sizes, int n_in,
                              void* d_out, int out_size, void* d_ws, size_t ws_size,
                              hipStream_t stream)
{
    const float* smplx_v       = (const float*)d_in[0];
    const float* object_v      = (const float*)d_in[1];
    const int*   smpl_part_idx = (const int*)d_in[2];
    const int*   obj_part_idx  = (const int*)d_in[3];
    const int*   batch_idx     = (const int*)d_in[4];
    float*       out           = (float*)d_out;

    float* partial = (float*)d_ws;   // GRID floats

    cl_onepass<<<GRID, BLK, 0, stream>>>(
        smplx_v, object_v, smpl_part_idx, obj_part_idx, batch_idx, partial);
    cl_final<<<1, GRID, 0, stream>>>(partial, out);
}

// Round 9
// 21.344 us; speedup vs baseline: 1.2385x; 1.2385x over previous
//
#include <hip/hip_runtime.h>
#include <float.h>
#include <math.h>

// Problem constants (from reference)
constexpr int B  = 16;
constexpr int VS = 10475;
constexpr int VO = 8192;
constexpr int K  = 64;
constexpr int PS = 1024;
constexpr int PO = 2048;

// Geometry: R6 structure, but QPB=128 -> GRID=512 = 2 blocks/CU so that
// gather + LDS latency of one block hides under the sibling block's compute.
// Block = (k, 128-query chunk); all 2048 objects of k staged in LDS.
// 8 half-wave jgroups x 256 objects; each lane owns 4 queries (2 packed pairs).
constexpr int BLK  = 256;
constexpr int QPB  = 128;              // queries per block
constexpr int GRID = K * (PS / QPB);   // 512
constexpr int NG   = 8;                // jgroups (half-waves) per block
constexpr int JPG  = PO / NG;          // 256 objects per jgroup
constexpr int QL   = QPB / 32;         // 4 queries per lane (2 pairs)

typedef float v2f __attribute__((ext_vector_type(2)));
typedef float v4f __attribute__((ext_vector_type(4)));

// ---------------- kernel 1: full min + block partial sum ----------------

__global__ __launch_bounds__(BLK)
void cl_onepass(const float* __restrict__ smplx_v,
                const float* __restrict__ object_v,
                const int*   __restrict__ spi,
                const int*   __restrict__ opi,
                const int*   __restrict__ bidx,
                float*       __restrict__ partial)   // [GRID]
{
    __shared__ v4f    so[PO];        // (x,y,z, 0.5*|o|^2) -> 32 KiB
    __shared__ float4 qld[QPB];      // (x,y,z, |s|^2)     ->  2 KiB
    __shared__ float  red[NG][QPB];  //                    ->  4 KiB
    __shared__ float  rsum[BLK];     //                    ->  1 KiB

    const int bk  = blockIdx.x;
    const int tid = threadIdx.x;
    const int k   = bk >> 3;         // 8 blocks per k
    const int ic  = bk & 7;
    const int b   = bidx[k];

    // ---- gather: all 2048 objects of this k into LDS ----
    const float* __restrict__ ov = object_v + (size_t)b * VO * 3;
    #pragma unroll
    for (int r = 0; r < PO / BLK; ++r) {
        const int j  = r * BLK + tid;
        const int oj = opi[k * PO + j];
        const float x = ov[oj * 3 + 0];
        const float y = ov[oj * 3 + 1];
        const float z = ov[oj * 3 + 2];
        so[j] = (v4f){x, y, z, 0.5f * (x * x + y * y + z * z)};
    }
    // ---- gather: this block's 128 queries ----
    if (tid < QPB) {
        const int i  = ic * QPB + tid;
        const int si = spi[k * PS + i];
        const float* __restrict__ sv = smplx_v + ((size_t)b * VS + si) * 3;
        const float x = sv[0], y = sv[1], z = sv[2];
        qld[tid] = make_float4(x, y, z, x * x + y * y + z * z);
    }
    __syncthreads();

    // ---- setup: lane owns 4 queries as 2 packed pairs ----
    const int g  = tid >> 5;         // jgroup 0..7 (half-wave)
    const int gl = tid & 31;
    const int qb = gl * QL;

    v2f nsx[2], nsy[2], nsz[2], mint[2];
    #pragma unroll
    for (int p = 0; p < 2; ++p) {
        const float4 qa = qld[qb + 2 * p];
        const float4 qc = qld[qb + 2 * p + 1];
        nsx[p] = (v2f){-qa.x, -qc.x};
        nsy[p] = (v2f){-qa.y, -qc.y};
        nsz[p] = (v2f){-qa.z, -qc.z};
        mint[p] = (v2f){FLT_MAX, FLT_MAX};
    }

    // ---- hot loop (R6-proven asm): min over this jgroup's 256 objects ----
    // t = 0.5*|o|^2 - s.o for 2 queries per v_pk_fma_f32; op_sel splats the
    // object components straight out of the (x,y),(z,w) register pairs.
    const v4f* __restrict__ sog = &so[g * JPG];
    #pragma unroll 8
    for (int j = 0; j < JPG; ++j) {
        const v4f o = sog[j];
        const v2f oxy = __builtin_shufflevector(o, o, 0, 1);  // (x,y)
        const v2f ozw = __builtin_shufflevector(o, o, 2, 3);  // (z,w)
        #pragma unroll
        for (int p = 0; p < 2; ++p) {
            v2f t;
            asm("v_pk_fma_f32 %0, %1, %2, %3 op_sel:[0,0,1] op_sel_hi:[0,1,1]"
                : "=v"(t) : "v"(oxy), "v"(nsx[p]), "v"(ozw));
            asm("v_pk_fma_f32 %0, %1, %2, %0 op_sel:[1,0,0] op_sel_hi:[1,1,1]"
                : "+v"(t) : "v"(oxy), "v"(nsy[p]));
            asm("v_pk_fma_f32 %0, %1, %2, %0 op_sel:[0,0,0] op_sel_hi:[0,1,1]"
                : "+v"(t) : "v"(ozw), "v"(nsz[p]));
            mint[p].x = fminf(mint[p].x, t.x);
            mint[p].y = fminf(mint[p].y, t.y);
        }
    }

    // ---- cross-jgroup min via LDS ----
    #pragma unroll
    for (int p = 0; p < 2; ++p) {
        red[g][qb + 2 * p]     = mint[p].x;
        red[g][qb + 2 * p + 1] = mint[p].y;
    }
    __syncthreads();

    // thread t (t < QPB) finalizes query t of this block
    float d = 0.0f;
    if (tid < QPB) {
        float m = red[0][tid];
        #pragma unroll
        for (int g2 = 1; g2 < NG; ++g2) m = fminf(m, red[g2][tid]);
        const float s2q = qld[tid].w;
        d = sqrtf(fmaxf(fmaf(2.0f, m, s2q), 0.0f));
    }

    // ---- deterministic block tree-sum ----
    rsum[tid] = d;
    __syncthreads();
    for (int s = BLK / 2; s > 0; s >>= 1) {
        if (tid < s) rsum[tid] += rsum[tid + s];
        __syncthreads();
    }
    if (tid == 0) partial[bk] = rsum[0];
}

// ---------------- kernel 2: final 512 -> 1 reduce (one wave) ----------------

__global__ __launch_bounds__(64)
void cl_final(const float* __restrict__ partial, float* __restrict__ out)
{
    const int t = threadIdx.x;
    const float4 a = ((const float4*)partial)[t];        // lanes 0..63 -> 256
    const float4 c = ((const float4*)partial)[t + 64];   // next 256
    float v = ((a.x + a.y) + (a.z + a.w)) + ((c.x + c.y) + (c.z + c.w));
    #pragma unroll
    for (int off = 32; off > 0; off >>= 1)
        v += __shfl_down(v, off, 64);
    if (t == 0) out[0] = v * (1.0f / (float)(K * PS));
}

// ---------------- launcher ----------------

extern "C" void kernel_launch(void* const* d_in, const int* in_sizes, int n_in,
                              void* d_out, int out_size, void* d_ws, size_t ws_size,
                              hipStream_t stream)
{
    const float* smplx_v       = (const float*)d_in[0];
    const float* object_v      = (const float*)d_in[1];
    const int*   smpl_part_idx = (const int*)d_in[2];
    const int*   obj_part_idx  = (const int*)d_in[3];
    const int*   batch_idx     = (const int*)d_in[4];
    float*       out           = (float*)d_out;

    float* partial = (float*)d_ws;   // GRID floats

    cl_onepass<<<GRID, BLK, 0, stream>>>(
        smplx_v, object_v, smpl_part_idx, obj_part_idx, batch_idx, partial);
    cl_final<<<1, 64, 0, stream>>>(partial, out);
}